// Round 8
// baseline (363.467 us; speedup 1.0000x reference)
//
#include <hip/hip_runtime.h>
#include <hip/hip_bf16.h>
#include <math.h>

typedef __hip_bfloat16 bf16;
typedef unsigned short u16;
typedef __attribute__((ext_vector_type(8))) short bf16x8;
typedef __attribute__((ext_vector_type(4))) float f32x4;

#define L_SEQ 256
#define NB 4
#define EMB 768
#define NH 12
#define DFF 3072
#define HD 64

__device__ __forceinline__ float ldE(const void* p, size_t i, int f32) {
    return f32 ? ((const float*)p)[i] : __bfloat162float(((const bf16*)p)[i]);
}
__device__ __forceinline__ float b2f(u16 v) { return __uint_as_float(((unsigned)v) << 16); }
__device__ __forceinline__ u16 f2b(float v) {
    bf16 h = __float2bfloat16(v);
    return *(u16*)&h;
}

// Runtime input dtype detect: fp32 words read as bf16 halves -> huge exponents.
__global__ void detect_kernel(const void* __restrict__ src, int* __restrict__ flagp) {
    __shared__ int cnt[256];
    int t = threadIdx.x;
    unsigned w = ((const unsigned*)src)[t];
    unsigned e = ((w & 0xFFFFu) >> 7) & 0xFFu;
    cnt[t] = (e >= 0xC3u) ? 1 : 0;
    __syncthreads();
    for (int off = 128; off; off >>= 1) {
        if (t < off) cnt[t] += cnt[t + off];
        __syncthreads();
    }
    if (t == 0) *flagp = (cnt[0] > 8) ? 1 : 0;
}

// Stage 8 contiguous elems of a (runtime-dtype) tensor into LDS as bf16.
__device__ __forceinline__ void stage8(u16* dst, const void* s, size_t off, int f32) {
    if (f32) {
        const float* sf = (const float*)s + off;
        float4 a = *(const float4*)sf;
        float4 b = *(const float4*)(sf + 4);
        u16 t[8] = {f2b(a.x), f2b(a.y), f2b(a.z), f2b(a.w),
                    f2b(b.x), f2b(b.y), f2b(b.z), f2b(b.w)};
        *(uint4*)dst = *(uint4*)t;
    } else {
        *(uint4*)dst = *(const uint4*)((const u16*)s + off);
    }
}

// MFMA bf16 GEMM, 64x128 tile (M=64 x N=128), 4 waves, wave = 64x32 (4x2 frags).
// A/W staged from runtime-dtype tensors directly (fp32 converted in-flight).
// grid: x = N/128, y = M/64 (=16), z = split-K index. lda = row stride (elems).
// MODE 0: QKV fused (W0..2 = q/k/v weights, b0..2 = biases); q scaled 0.125;
//         V written TRANSPOSED vt[(n*EMB+e)*L+i]
// MODE 2: + bias b0, exact GELU -> outB0 bf16 (stride DFF)
// MODE 4: partial, no bias -> fp32 outF + z*1024*EMB
// MODE 5: partial, no bias -> atomicAdd into outF
template <int MODE, int AEXT>
__global__ __launch_bounds__(256) void mfma_gemm(
        const void* __restrict__ A, const void* __restrict__ W0,
        const void* __restrict__ W1, const void* __restrict__ W2,
        const void* __restrict__ b0, const void* __restrict__ b1,
        const void* __restrict__ b2,
        u16* __restrict__ outB0, u16* __restrict__ outB1, u16* __restrict__ outB2,
        float* __restrict__ outF,
        int K, int lda, int ksplit, const int* __restrict__ flagp) {
    const int f32 = *flagp;
    const int af32 = AEXT ? f32 : 0;
    __shared__ u16 As[64][40];
    __shared__ u16 Ws[128][40];
    int tid = threadIdx.x;
    int wave = tid >> 6, lane = tid & 63;
    int quad = lane >> 4, col = lane & 15;
    int m0 = blockIdx.y * 64, n0 = blockIdx.x * 128;
    int z = blockIdx.z;
    size_t zoff = (size_t)z * ksplit;
    // W tensor select (QKV: 128-col tiles never cross the 768 boundaries)
    const void* Wt = W0;
    int nb = n0, sel = 0;
    if (MODE == 0) {
        sel = n0 / EMB;
        Wt = sel == 0 ? W0 : (sel == 1 ? W1 : W2);
        nb = n0 - sel * EMB;
    }
    f32x4 acc[4][2];
    #pragma unroll
    for (int a = 0; a < 4; ++a)
        #pragma unroll
        for (int b = 0; b < 2; ++b) acc[a][b] = (f32x4){0.f, 0.f, 0.f, 0.f};
    for (int k0 = 0; k0 < K; k0 += 32) {
        #pragma unroll
        for (int it = 0; it < 3; ++it) {
            int l = tid + it * 256;
            if (l < 256) {
                int r = l >> 2, c8 = (l & 3) * 8;
                stage8(&As[r][c8], A, (size_t)(m0 + r) * lda + k0 + c8 + zoff, af32);
            } else {
                int l2 = l - 256;
                int r = l2 >> 2, c8 = (l2 & 3) * 8;
                stage8(&Ws[r][c8], Wt, (size_t)(nb + r) * lda + k0 + c8 + zoff, f32);
            }
        }
        __syncthreads();
        bf16x8 af[4], bfr[2];
        #pragma unroll
        for (int mi = 0; mi < 4; ++mi)
            af[mi] = __builtin_bit_cast(bf16x8, *(const uint4*)&As[mi * 16 + col][quad * 8]);
        #pragma unroll
        for (int ni = 0; ni < 2; ++ni)
            bfr[ni] = __builtin_bit_cast(bf16x8, *(const uint4*)&Ws[wave * 32 + ni * 16 + col][quad * 8]);
        #pragma unroll
        for (int mi = 0; mi < 4; ++mi)
            #pragma unroll
            for (int ni = 0; ni < 2; ++ni)
                acc[mi][ni] = __builtin_amdgcn_mfma_f32_16x16x32_bf16(
                    af[mi], bfr[ni], acc[mi][ni], 0, 0, 0);
        __syncthreads();
    }
    #pragma unroll
    for (int mi = 0; mi < 4; ++mi)
        #pragma unroll
        for (int ni = 0; ni < 2; ++ni)
            #pragma unroll
            for (int reg = 0; reg < 4; ++reg) {
                int rr = m0 + mi * 16 + quad * 4 + reg;
                int cc = n0 + wave * 32 + ni * 16 + col;
                float v = acc[mi][ni][reg];
                if (MODE == 0) {
                    int cl = cc - sel * EMB;
                    const void* bt = sel == 0 ? b0 : (sel == 1 ? b1 : b2);
                    v += ldE(bt, cl, f32);
                    if (sel == 0) {
                        outB0[(size_t)rr * EMB + cl] = f2b(v * 0.125f);
                    } else if (sel == 1) {
                        outB1[(size_t)rr * EMB + cl] = f2b(v);
                    } else {
                        // vt[(n*EMB + e)*L + i], rr = i*NB + n
                        outB2[((size_t)(rr & 3) * EMB + cl) * L_SEQ + (rr >> 2)] = f2b(v);
                    }
                } else if (MODE == 2) {
                    v += ldE(b0, cc, f32);
                    v = 0.5f * v * (1.0f + erff(v * 0.70710678118654752f));
                    outB0[(size_t)rr * DFF + cc] = f2b(v);
                } else if (MODE == 4) {
                    outF[(size_t)z * 1024 * EMB + (size_t)rr * EMB + cc] = v;
                } else {
                    atomicAdd(&outF[(size_t)rr * EMB + cc], v);
                }
            }
}

// qp_b[n,i,h,c] (bf16, h padded to 16) = sum_d q[i,n,h,d] p_w[h*64+d, c]
// qpb[n,h,i] = q . p_b   (q pre-scaled by 0.125 in QKV epilogue)
__global__ void qp_kernel(const u16* __restrict__ qb, const void* __restrict__ p_w,
                          const void* __restrict__ p_b, u16* __restrict__ qp_b,
                          float* __restrict__ qpb, const int* __restrict__ flagp) {
    const int f32 = *flagp;
    int blk = blockIdx.x;                // (n*NH+h)*L + i
    int i = blk & 255;
    int h = (blk >> 8) % NH;
    int n = blk / (256 * NH);
    int t = threadIdx.x;                 // 0..63
    __shared__ float qs[64];
    qs[t] = b2f(qb[(size_t)(i * NB + n) * EMB + h * HD + t]);
    __syncthreads();
    float acc = 0.f;
    #pragma unroll 16
    for (int d = 0; d < 64; ++d)
        acc += qs[d] * ldE(p_w, (size_t)(h * HD + d) * HD + t, f32);
    qp_b[(((size_t)(n * L_SEQ + i)) * 16 + h) * 64 + t] = f2b(acc);
    float v = qs[t] * ldE(p_b, h * HD + t, f32);
    #pragma unroll
    for (int off = 32; off; off >>= 1) v += __shfl_down(v, off);
    if (t == 0) qpb[blk] = v;
}

// S[n,h,i,j] = sum_c qp_b[n,i,h,c] * pos[n,i,j,c] + qpb[n,h,i]
__global__ __launch_bounds__(256) void s2_mfma(
        const u16* __restrict__ qp_b, const float* __restrict__ qpb,
        const void* __restrict__ pos, float* __restrict__ S,
        const int* __restrict__ flagp) {
    const int f32 = *flagp;
    int wid = (blockIdx.x << 2) + (threadIdx.x >> 6);   // n*L + i
    int i = wid & 255, n = wid >> 8;
    int lane = threadIdx.x & 63;
    int quad = lane >> 4, col = lane & 15;
    const u16* qprow = qp_b + (((size_t)wid) * 16 + col) * 64;
    bf16x8 a0 = __builtin_bit_cast(bf16x8, *(const uint4*)(qprow + quad * 8));
    bf16x8 a1 = __builtin_bit_cast(bf16x8, *(const uint4*)(qprow + 32 + quad * 8));
    float qpb_r[4];
    #pragma unroll
    for (int reg = 0; reg < 4; ++reg) {
        int h = quad * 4 + reg;
        qpb_r[reg] = (h < NH) ? qpb[((size_t)n * NH + h) * L_SEQ + i] : 0.f;
    }
    #pragma unroll 4
    for (int t = 0; t < 16; ++t) {
        int j = t * 16 + col;
        size_t pbase = ((size_t)(n * L_SEQ + i) * L_SEQ + j) * HD;
        bf16x8 b0, b1;
        if (f32) {
            const float* pf = (const float*)pos + pbase;
            u16 tmp[16];
            #pragma unroll
            for (int c = 0; c < 8; ++c) tmp[c] = f2b(pf[quad * 8 + c]);
            #pragma unroll
            for (int c = 0; c < 8; ++c) tmp[8 + c] = f2b(pf[32 + quad * 8 + c]);
            b0 = *(bf16x8*)tmp;
            b1 = *(bf16x8*)(tmp + 8);
        } else {
            const u16* pb = (const u16*)pos + pbase;
            b0 = __builtin_bit_cast(bf16x8, *(const uint4*)(pb + quad * 8));
            b1 = __builtin_bit_cast(bf16x8, *(const uint4*)(pb + 32 + quad * 8));
        }
        f32x4 acc = (f32x4){0.f, 0.f, 0.f, 0.f};
        acc = __builtin_amdgcn_mfma_f32_16x16x32_bf16(a0, b0, acc, 0, 0, 0);
        acc = __builtin_amdgcn_mfma_f32_16x16x32_bf16(a1, b1, acc, 0, 0, 0);
        if (quad < 3) {
            #pragma unroll
            for (int reg = 0; reg < 4; ++reg) {
                int h = quad * 4 + reg;
                S[(((size_t)n * NH + h) * L_SEQ + i) * L_SEQ + j] = acc[reg] + qpb_r[reg];
            }
        }
    }
}

// MFMA attention: scores = q.k^T + S, softmax (register+shuffle), ctx = P@V.
// Block per (n,h,it): 2 waves, wave owns 16 i-rows (32 rows/block, 384 blocks).
__global__ __launch_bounds__(128) void attn3_kernel(
        const u16* __restrict__ qb, const u16* __restrict__ kb,
        const u16* __restrict__ vt, const float* __restrict__ S,
        u16* __restrict__ ctxb) {
    __shared__ u16 p_lds[2][16][268];
    int b = blockIdx.x;
    int n = b / 96, rem = b % 96, h = rem >> 3, it = rem & 7;
    int wave = threadIdx.x >> 6, lane = threadIdx.x & 63;
    int quad = lane >> 4, col = lane & 15;
    int i0 = it * 32 + wave * 16;

    const u16* qrow = qb + ((size_t)(i0 + col) * NB + n) * EMB + h * HD;
    bf16x8 a0 = __builtin_bit_cast(bf16x8, *(const uint4*)(qrow + quad * 8));
    bf16x8 a1 = __builtin_bit_cast(bf16x8, *(const uint4*)(qrow + 32 + quad * 8));

    f32x4 sc[16];
    #pragma unroll
    for (int t = 0; t < 16; ++t) {
        const u16* krow = kb + ((size_t)(t * 16 + col) * NB + n) * EMB + h * HD;
        bf16x8 b0 = __builtin_bit_cast(bf16x8, *(const uint4*)(krow + quad * 8));
        bf16x8 b1 = __builtin_bit_cast(bf16x8, *(const uint4*)(krow + 32 + quad * 8));
        f32x4 acc = (f32x4){0.f, 0.f, 0.f, 0.f};
        acc = __builtin_amdgcn_mfma_f32_16x16x32_bf16(a0, b0, acc, 0, 0, 0);
        acc = __builtin_amdgcn_mfma_f32_16x16x32_bf16(a1, b1, acc, 0, 0, 0);
        sc[t] = acc;
    }

    #pragma unroll
    for (int reg = 0; reg < 4; ++reg) {
        const float* Srow = S + (((size_t)n * NH + h) * L_SEQ + i0 + quad * 4 + reg) * L_SEQ + col;
        float m = -1e30f;
        #pragma unroll
        for (int t = 0; t < 16; ++t) {
            float v = sc[t][reg] + Srow[t * 16];
            sc[t][reg] = v;
            m = fmaxf(m, v);
        }
        #pragma unroll
        for (int off = 1; off < 16; off <<= 1) m = fmaxf(m, __shfl_xor(m, off));
        float sum = 0.f;
        #pragma unroll
        for (int t = 0; t < 16; ++t) {
            float e = __expf(sc[t][reg] - m);
            sc[t][reg] = e;
            sum += e;
        }
        #pragma unroll
        for (int off = 1; off < 16; off <<= 1) sum += __shfl_xor(sum, off);
        float inv = 1.0f / sum;
        #pragma unroll
        for (int t = 0; t < 16; ++t)
            p_lds[wave][quad * 4 + reg][t * 16 + col] = f2b(sc[t][reg] * inv);
    }

    bf16x8 ap[8];
    #pragma unroll
    for (int kt = 0; kt < 8; ++kt)
        ap[kt] = __builtin_bit_cast(bf16x8, *(const uint4*)&p_lds[wave][col][kt * 32 + quad * 8]);
    #pragma unroll
    for (int nt = 0; nt < 4; ++nt) {
        const u16* vrow = vt + ((size_t)n * EMB + h * HD + nt * 16 + col) * L_SEQ;
        f32x4 acc = (f32x4){0.f, 0.f, 0.f, 0.f};
        #pragma unroll
        for (int kt = 0; kt < 8; ++kt) {
            bf16x8 bp = __builtin_bit_cast(bf16x8, *(const uint4*)(vrow + kt * 32 + quad * 8));
            acc = __builtin_amdgcn_mfma_f32_16x16x32_bf16(ap[kt], bp, acc, 0, 0, 0);
        }
        #pragma unroll
        for (int reg = 0; reg < 4; ++reg) {
            int ii = i0 + quad * 4 + reg;
            ctxb[((size_t)ii * NB + n) * EMB + h * HD + nt * 16 + col] = f2b(acc[reg]);
        }
    }
}

// ln1: y = p0+p1+p2 + src + out_bias; LN -> x1b (bf16); y2 = LN_out + lin2_bias.
__global__ void ln1_kernel(const float* __restrict__ parts, const void* __restrict__ src,
                           const void* __restrict__ out_b, const void* __restrict__ lin2_b,
                           const void* __restrict__ g, const void* __restrict__ b,
                           u16* __restrict__ x1b, float* __restrict__ y2,
                           const int* __restrict__ flagp) {
    const int f32 = *flagp;
    int r = blockIdx.x;
    int t = threadIdx.x;
    __shared__ float red[256];
    const size_t PS = (size_t)1024 * EMB;
    float x[3];
    #pragma unroll
    for (int p = 0; p < 3; ++p) {
        int e = t + p * 256;
        size_t oi = (size_t)r * EMB + e;
        x[p] = parts[oi] + parts[PS + oi] + parts[2 * PS + oi]
             + ldE(src, oi, f32) + ldE(out_b, e, f32);
    }
    red[t] = x[0] + x[1] + x[2];
    __syncthreads();
    for (int off = 128; off; off >>= 1) {
        if (t < off) red[t] += red[t + off];
        __syncthreads();
    }
    float mean = red[0] * (1.0f / EMB);
    __syncthreads();
    float d0 = x[0] - mean, d1 = x[1] - mean, d2 = x[2] - mean;
    red[t] = d0 * d0 + d1 * d1 + d2 * d2;
    __syncthreads();
    for (int off = 128; off; off >>= 1) {
        if (t < off) red[t] += red[t + off];
        __syncthreads();
    }
    float rstd = rsqrtf(red[0] * (1.0f / EMB) + 1e-5f);
    float vs[3] = {d0, d1, d2};
    #pragma unroll
    for (int p = 0; p < 3; ++p) {
        int e = t + p * 256;
        float v = vs[p] * rstd * ldE(g, e, f32) + ldE(b, e, f32);
        size_t oi = (size_t)r * EMB + e;
        x1b[oi] = f2b(v);
        y2[oi] = v + ldE(lin2_b, e, f32);
    }
}

// ln2 (final): LN(y2) -> d_out runtime dtype.
__global__ void ln2_kernel(const float* __restrict__ X, const void* __restrict__ g,
                           const void* __restrict__ b, void* __restrict__ outAny,
                           const int* __restrict__ flagp) {
    const int f32 = *flagp;
    int r = blockIdx.x;
    int t = threadIdx.x;
    __shared__ float red[256];
    float x0 = X[(size_t)r * EMB + t];
    float x1 = X[(size_t)r * EMB + t + 256];
    float x2 = X[(size_t)r * EMB + t + 512];
    red[t] = x0 + x1 + x2;
    __syncthreads();
    for (int off = 128; off; off >>= 1) {
        if (t < off) red[t] += red[t + off];
        __syncthreads();
    }
    float mean = red[0] * (1.0f / EMB);
    __syncthreads();
    float d0 = x0 - mean, d1 = x1 - mean, d2 = x2 - mean;
    red[t] = d0 * d0 + d1 * d1 + d2 * d2;
    __syncthreads();
    for (int off = 128; off; off >>= 1) {
        if (t < off) red[t] += red[t + off];
        __syncthreads();
    }
    float rstd = rsqrtf(red[0] * (1.0f / EMB) + 1e-5f);
    float vs[3] = {d0, d1, d2};
    #pragma unroll
    for (int p = 0; p < 3; ++p) {
        int e = t + p * 256;
        float v = vs[p] * rstd * ldE(g, e, f32) + ldE(b, e, f32);
        size_t oi = (size_t)r * EMB + e;
        if (f32) ((float*)outAny)[oi] = v;
        else     ((bf16*)outAny)[oi] = __float2bfloat16(v);
    }
}

extern "C" void kernel_launch(void* const* d_in, const int* in_sizes, int n_in,
                              void* d_out, int out_size, void* d_ws, size_t ws_size,
                              hipStream_t stream) {
    const void* src    = d_in[0];
    const void* pos    = d_in[1];
    const void* q_w    = d_in[2];
    const void* q_b    = d_in[3];
    const void* k_w    = d_in[4];
    const void* k_b    = d_in[5];
    const void* v_w    = d_in[6];
    const void* v_b    = d_in[7];
    const void* p_w    = d_in[8];
    const void* p_b    = d_in[9];
    const void* out_w  = d_in[10];
    const void* out_b  = d_in[11];
    const void* lin1_w = d_in[12];
    const void* lin1_b = d_in[13];
    const void* lin2_w = d_in[14];
    const void* lin2_b = d_in[15];
    const void* n1_g   = d_in[16];
    const void* n1_b   = d_in[17];
    const void* n2_g   = d_in[18];
    const void* n2_b   = d_in[19];

    float* f = (float*)d_ws;
    // flat layout (float slots), ~42 MB — no overlays
    int*   flagp = (int*)f;                              // 16
    u16*   qbp   = (u16*)(f + 16);                       // 393216 f
    u16*   kbp   = (u16*)(f + 393232);                   // 393216 f
    u16*   vtb   = (u16*)(f + 786448);                   // 393216 f  vt[n][e][i]
    u16*   qp_b  = (u16*)(f + 1179664);                  // 524288 f
    float* qpb   = f + 1703952;                          // 12288
    float* S     = f + 1716240;                          // 3145728
    u16*   ctxb  = (u16*)(f + 4861968);                  // 393216 f
    float* parts = f + 5255184;                          // 3 x 786432 = 2359296
    u16*   x1b   = (u16*)(f + 7614480);                  // 393216 f
    float* y2    = f + 8007696;                          // 786432
    u16*   ffb   = (u16*)(f + 8794128);                  // 1572864 f (end 10366992)

    detect_kernel<<<1, 256, 0, stream>>>(src, flagp);

    // QKV fused GEMM straight from external tensors; V written transposed
    mfma_gemm<0, 1><<<dim3(18, 16), 256, 0, stream>>>(
        src, q_w, k_w, v_w, q_b, k_b, v_b, qbp, kbp, vtb, nullptr,
        EMB, EMB, 0, flagp);

    // position scores
    qp_kernel<<<NB * NH * L_SEQ, 64, 0, stream>>>(qbp, p_w, p_b, qp_b, qpb, flagp);
    s2_mfma<<<NB * L_SEQ / 4, 256, 0, stream>>>(qp_b, qpb, pos, S, flagp);

    // MFMA attention
    attn3_kernel<<<NB * NH * 8, 128, 0, stream>>>(qbp, kbp, vtb, S, ctxb);

    // out projection, split-K=3 -> 3 fp32 partials (bias+residual folded into ln1)
    mfma_gemm<4, 0><<<dim3(6, 16, 3), 256, 0, stream>>>(
        ctxb, out_w, nullptr, nullptr, nullptr, nullptr, nullptr,
        nullptr, nullptr, nullptr, parts, 256, EMB, 256, flagp);

    // ln1: reduce partials + src + out_bias, LN -> x1b; y2 = LN + lin2_bias
    ln1_kernel<<<1024, 256, 0, stream>>>(parts, src, out_b, lin2_b, n1_g, n1_b,
                                         x1b, y2, flagp);

    // lin1 + GELU -> ffb
    mfma_gemm<2, 0><<<dim3(24, 16), 256, 0, stream>>>(
        x1b, lin1_w, nullptr, nullptr, lin1_b, nullptr, nullptr,
        ffb, nullptr, nullptr, nullptr, EMB, EMB, 0, flagp);

    // lin2, split-K=4, atomic accumulate into y2 (pre-initialized by ln1)
    mfma_gemm<5, 0><<<dim3(6, 16, 4), 256, 0, stream>>>(
        ffb, lin2_w, nullptr, nullptr, nullptr, nullptr, nullptr,
        nullptr, nullptr, nullptr, y2, 768, DFF, 768, flagp);

    ln2_kernel<<<1024, 256, 0, stream>>>(y2, n2_g, n2_b, d_out, flagp);
}

// Round 9
// 315.985 us; speedup vs baseline: 1.1503x; 1.1503x over previous
//
#include <hip/hip_runtime.h>
#include <hip/hip_bf16.h>
#include <math.h>

typedef __hip_bfloat16 bf16;
typedef unsigned short u16;
typedef __attribute__((ext_vector_type(8))) short bf16x8;
typedef __attribute__((ext_vector_type(4))) float f32x4;

#define L_SEQ 256
#define NB 4
#define EMB 768
#define NH 12
#define DFF 3072
#define HD 64

__device__ __forceinline__ float ldE(const void* p, size_t i, int f32) {
    return f32 ? ((const float*)p)[i] : __bfloat162float(((const bf16*)p)[i]);
}
__device__ __forceinline__ float b2f(u16 v) { return __uint_as_float(((unsigned)v) << 16); }
__device__ __forceinline__ u16 f2b(float v) {
    bf16 h = __float2bfloat16(v);
    return *(u16*)&h;
}

__device__ __forceinline__ void cvt8(u16* dst, const void* s, size_t off, int f32) {
    if (f32) {
        const float* sf = (const float*)s + off;
        #pragma unroll
        for (int t = 0; t < 8; ++t) dst[t] = f2b(sf[t]);
    } else {
        *(uint4*)dst = *(const uint4*)((const u16*)s + off);
    }
}

// Packs all weights to bf16, biases to fp32, p_w to transposed p_wT[65][768]
// (row 64 = p_b). Dtype flag computed per-block from src[0..255] words
// (fp32-as-bf16 halves -> huge exponents); thread 0 of every block writes flagp.
__global__ void pack_all(u16* __restrict__ xb, u16* __restrict__ wqkv,
                         u16* __restrict__ owb, u16* __restrict__ l1b,
                         u16* __restrict__ l2b, float* __restrict__ biasf,
                         u16* __restrict__ p_wT,
                         const void* src, const void* qw, const void* kw, const void* vw,
                         const void* ow, const void* l1w, const void* l2w,
                         const void* qb, const void* kb, const void* vb,
                         const void* ob, const void* b1, const void* b2,
                         const void* pw, const void* pb,
                         int* __restrict__ flagp) {
    __shared__ int cnt[256];
    int t = threadIdx.x;
    {
        unsigned w = ((const unsigned*)src)[t];
        unsigned e = ((w & 0xFFFFu) >> 7) & 0xFFu;
        cnt[t] = (e >= 0xC3u) ? 1 : 0;
        __syncthreads();
        for (int off = 128; off; off >>= 1) {
            if (t < off) cnt[t] += cnt[t + off];
            __syncthreads();
        }
    }
    const int f32 = (cnt[0] > 8) ? 1 : 0;
    int b = blockIdx.x;
    if (b == 0 && t == 0) *flagp = f32;
    if (b >= 3867) {                       // p_wT: 65*768 = 49920 elems, 8/thread
        int o = (b - 3867) * 256 + t;
        if (o >= 6240) return;
        int idx = o * 8;
        int c = idx / EMB, e0 = idx % EMB;
        u16 tmp[8];
        if (c < 64) {
            #pragma unroll
            for (int k = 0; k < 8; ++k) tmp[k] = f2b(ldE(pw, (size_t)(e0 + k) * 64 + c, f32));
        } else {
            #pragma unroll
            for (int k = 0; k < 8; ++k) tmp[k] = f2b(ldE(pb, e0 + k, f32));
        }
        *(uint4*)(p_wT + idx) = *(uint4*)tmp;
        return;
    }
    if (b >= 3840) {                       // biases -> fp32
        int o = (b - 3840) * 256 + t;
        if (o >= 6912) return;
        float v;
        if (o < 768)       v = ldE(qb, o, f32);
        else if (o < 1536) v = ldE(kb, o - 768, f32);
        else if (o < 2304) v = ldE(vb, o - 1536, f32);
        else if (o < 3072) v = ldE(ob, o - 2304, f32);
        else if (o < 6144) v = ldE(b1, o - 3072, f32);
        else               v = ldE(b2, o - 6144, f32);
        biasf[o] = v;
        return;
    }
    int gid = b * 256 + t;
    u16 tmp[8];
    if (gid < 98304) {
        size_t idx = (size_t)gid * 8;
        cvt8(tmp, src, idx, f32);
        *(uint4*)(xb + idx) = *(uint4*)tmp;
    } else if (gid < 319488) {
        size_t idx = (size_t)(gid - 98304) * 8;
        int r = (int)(idx / EMB);
        const void* s;
        size_t off;
        if (r < EMB)          { s = qw; off = idx; }
        else if (r < 2 * EMB) { s = kw; off = idx - (size_t)EMB * EMB; }
        else                  { s = vw; off = idx - (size_t)2 * EMB * EMB; }
        cvt8(tmp, s, off, f32);
        *(uint4*)(wqkv + idx) = *(uint4*)tmp;
    } else if (gid < 393216) {
        size_t idx = (size_t)(gid - 319488) * 8;
        cvt8(tmp, ow, idx, f32);
        *(uint4*)(owb + idx) = *(uint4*)tmp;
    } else if (gid < 688128) {
        size_t idx = (size_t)(gid - 393216) * 8;
        cvt8(tmp, l1w, idx, f32);
        *(uint4*)(l1b + idx) = *(uint4*)tmp;
    } else {
        size_t idx = (size_t)(gid - 688128) * 8;
        cvt8(tmp, l2w, idx, f32);
        *(uint4*)(l2b + idx) = *(uint4*)tmp;
    }
}

// MFMA bf16 GEMM: C[M,N] = A[M,K] @ W[N,K]^T. 128x128 tile, 4 waves (R7-proven).
// MODE 0: +bias, qkv split -> q,k bf16 (q scaled 0.125); V TRANSPOSED vt[n][e][i]
// MODE 2: +bias, GELU -> outB0 bf16, stride DFF
// MODE 4: partial (no bias) -> fp32 to (z ? outF2 : outF)
// MODE 5: partial (no bias) -> atomicAdd into outF
template <int MODE>
__global__ __launch_bounds__(256) void mfma_gemm(
        const u16* __restrict__ A, const u16* __restrict__ W,
        const float* __restrict__ biasf,
        u16* __restrict__ outB0, u16* __restrict__ outB1, u16* __restrict__ outB2,
        float* __restrict__ outF, float* __restrict__ outF2,
        int K, int lda, int ksplit) {
    __shared__ u16 As[128][40];
    __shared__ u16 Ws[128][40];
    int tid = threadIdx.x;
    int wave = tid >> 6, lane = tid & 63;
    int quad = lane >> 4, col = lane & 15;
    int m0 = blockIdx.y * 128, n0 = blockIdx.x * 128;
    int z = blockIdx.z;
    const u16* Ap = A + (size_t)z * ksplit;
    const u16* Wp = W + (size_t)z * ksplit;
    int wm = (wave >> 1) * 64, wn = (wave & 1) * 64;
    f32x4 acc[4][4];
    #pragma unroll
    for (int a = 0; a < 4; ++a)
        #pragma unroll
        for (int b = 0; b < 4; ++b) acc[a][b] = (f32x4){0.f, 0.f, 0.f, 0.f};
    for (int k0 = 0; k0 < K; k0 += 32) {
        #pragma unroll
        for (int it = 0; it < 2; ++it) {
            int l = tid + it * 256;
            int r = l >> 2, c4 = (l & 3) * 8;
            *(uint4*)&As[r][c4] = *(const uint4*)&Ap[(size_t)(m0 + r) * lda + k0 + c4];
            *(uint4*)&Ws[r][c4] = *(const uint4*)&Wp[(size_t)(n0 + r) * lda + k0 + c4];
        }
        __syncthreads();
        bf16x8 af[4], bfr[4];
        #pragma unroll
        for (int mi = 0; mi < 4; ++mi)
            af[mi] = __builtin_bit_cast(bf16x8, *(const uint4*)&As[wm + mi * 16 + col][quad * 8]);
        #pragma unroll
        for (int ni = 0; ni < 4; ++ni)
            bfr[ni] = __builtin_bit_cast(bf16x8, *(const uint4*)&Ws[wn + ni * 16 + col][quad * 8]);
        #pragma unroll
        for (int mi = 0; mi < 4; ++mi)
            #pragma unroll
            for (int ni = 0; ni < 4; ++ni)
                acc[mi][ni] = __builtin_amdgcn_mfma_f32_16x16x32_bf16(
                    af[mi], bfr[ni], acc[mi][ni], 0, 0, 0);
        __syncthreads();
    }
    #pragma unroll
    for (int mi = 0; mi < 4; ++mi)
        #pragma unroll
        for (int ni = 0; ni < 4; ++ni)
            #pragma unroll
            for (int reg = 0; reg < 4; ++reg) {
                int rr = m0 + wm + mi * 16 + quad * 4 + reg;
                int cc = n0 + wn + ni * 16 + col;
                float v = acc[mi][ni][reg];
                if (MODE == 0) {
                    v += biasf[cc];
                    if (cc < EMB) {
                        outB0[(size_t)rr * EMB + cc] = f2b(v * 0.125f);
                    } else if (cc < 2 * EMB) {
                        outB1[(size_t)rr * EMB + cc - EMB] = f2b(v);
                    } else {
                        outB2[((size_t)(rr & 3) * EMB + (cc - 2 * EMB)) * L_SEQ + (rr >> 2)] = f2b(v);
                    }
                } else if (MODE == 2) {
                    v += biasf[cc];
                    v = 0.5f * v * (1.0f + erff(v * 0.70710678118654752f));
                    outB0[(size_t)rr * DFF + cc] = f2b(v);
                } else if (MODE == 4) {
                    float* o = z ? outF2 : outF;
                    o[(size_t)rr * EMB + cc] = v;
                } else {
                    atomicAdd(&outF[(size_t)rr * EMB + cc], v);
                }
            }
}

// Fused qp + position scores. One wave per (n,i), 4 waves/block.
// Phase 1 (qp): masked block-diagonal GEMM qp[h][c] = sum_e q[e]*1[e in band_h]*p_wT[c][e],
//   M=16(h), K=768, N=80 (c=64 -> qpb via p_wT row 64 = p_b). ~120 MFMA/wave.
// Phase 2: S[n,h,i,j] = sum_c qp[h][c]*pos[n,i,j,c] + qpb[h] (R7 s2 body, A from LDS).
__global__ __launch_bounds__(256) void s2q_mfma(
        const u16* __restrict__ qbp, const u16* __restrict__ p_wT,
        const void* __restrict__ pos, float* __restrict__ S,
        const int* __restrict__ flagp) {
    const int f32 = *flagp;
    __shared__ u16 qp_l[4][16][68];     // per-wave; pad 68 -> conflict-free b128 reads
    __shared__ float qpb_l[4][16];
    int wave = threadIdx.x >> 6, lane = threadIdx.x & 63;
    int quad = lane >> 4, col = lane & 15;
    int wid = (blockIdx.x << 2) + wave;  // n*L + i
    int i = wid & 255, n = wid >> 8;
    const u16* qrow = qbp + (size_t)(i * NB + n) * EMB;

    // phase 1: qp GEMM
    f32x4 qpacc[5];
    #pragma unroll
    for (int nt = 0; nt < 5; ++nt) qpacc[nt] = (f32x4){0.f, 0.f, 0.f, 0.f};
    #pragma unroll
    for (int kt = 0; kt < 24; ++kt) {
        int owner = (4 * kt + quad) >> 3;
        uint4 av = (col == owner) ? *(const uint4*)(qrow + kt * 32 + quad * 8)
                                  : (uint4){0u, 0u, 0u, 0u};
        bf16x8 a = __builtin_bit_cast(bf16x8, av);
        #pragma unroll
        for (int nt = 0; nt < 5; ++nt) {
            bf16x8 bb = __builtin_bit_cast(bf16x8,
                *(const uint4*)(p_wT + (size_t)(nt * 16 + col) * EMB + kt * 32 + quad * 8));
            qpacc[nt] = __builtin_amdgcn_mfma_f32_16x16x32_bf16(a, bb, qpacc[nt], 0, 0, 0);
        }
    }
    // D layout: row h = quad*4+reg, col c = nt*16 + col -> LDS transpose to A-layout
    #pragma unroll
    for (int nt = 0; nt < 4; ++nt)
        #pragma unroll
        for (int reg = 0; reg < 4; ++reg)
            qp_l[wave][quad * 4 + reg][nt * 16 + col] = f2b(qpacc[nt][reg]);
    if (col == 0) {
        #pragma unroll
        for (int reg = 0; reg < 4; ++reg) qpb_l[wave][quad * 4 + reg] = qpacc[4][reg];
    }
    // same-wave LDS write->read: lgkmcnt-ordered, no barrier needed
    bf16x8 a0 = __builtin_bit_cast(bf16x8, *(const uint4*)&qp_l[wave][col][quad * 8]);
    bf16x8 a1 = __builtin_bit_cast(bf16x8, *(const uint4*)&qp_l[wave][col][32 + quad * 8]);
    float qpb_r[4];
    #pragma unroll
    for (int reg = 0; reg < 4; ++reg) qpb_r[reg] = qpb_l[wave][quad * 4 + reg];

    // phase 2: pos scores
    #pragma unroll 4
    for (int t = 0; t < 16; ++t) {
        int j = t * 16 + col;
        size_t pbase = ((size_t)(n * L_SEQ + i) * L_SEQ + j) * HD;
        bf16x8 b0, b1;
        if (f32) {
            const float* pf = (const float*)pos + pbase;
            u16 tmp[16];
            #pragma unroll
            for (int c = 0; c < 8; ++c) tmp[c] = f2b(pf[quad * 8 + c]);
            #pragma unroll
            for (int c = 0; c < 8; ++c) tmp[8 + c] = f2b(pf[32 + quad * 8 + c]);
            b0 = *(bf16x8*)tmp;
            b1 = *(bf16x8*)(tmp + 8);
        } else {
            const u16* pb = (const u16*)pos + pbase;
            b0 = __builtin_bit_cast(bf16x8, *(const uint4*)(pb + quad * 8));
            b1 = __builtin_bit_cast(bf16x8, *(const uint4*)(pb + 32 + quad * 8));
        }
        f32x4 acc = (f32x4){0.f, 0.f, 0.f, 0.f};
        acc = __builtin_amdgcn_mfma_f32_16x16x32_bf16(a0, b0, acc, 0, 0, 0);
        acc = __builtin_amdgcn_mfma_f32_16x16x32_bf16(a1, b1, acc, 0, 0, 0);
        if (quad < 3) {
            #pragma unroll
            for (int reg = 0; reg < 4; ++reg) {
                int h = quad * 4 + reg;
                S[(((size_t)n * NH + h) * L_SEQ + i) * L_SEQ + j] = acc[reg] + qpb_r[reg];
            }
        }
    }
}

// MFMA attention: scores = q.k^T + S, softmax (register+shuffle), ctx = P@V.
// Block per (n,h,it): 2 waves x 16 i-rows (384 blocks).
__global__ __launch_bounds__(128) void attn3_kernel(
        const u16* __restrict__ qb, const u16* __restrict__ kb,
        const u16* __restrict__ vt, const float* __restrict__ S,
        u16* __restrict__ ctxb) {
    __shared__ u16 p_lds[2][16][268];
    int b = blockIdx.x;
    int n = b / 96, rem = b % 96, h = rem >> 3, it = rem & 7;
    int wave = threadIdx.x >> 6, lane = threadIdx.x & 63;
    int quad = lane >> 4, col = lane & 15;
    int i0 = it * 32 + wave * 16;

    const u16* qrow = qb + ((size_t)(i0 + col) * NB + n) * EMB + h * HD;
    bf16x8 a0 = __builtin_bit_cast(bf16x8, *(const uint4*)(qrow + quad * 8));
    bf16x8 a1 = __builtin_bit_cast(bf16x8, *(const uint4*)(qrow + 32 + quad * 8));

    f32x4 sc[16];
    #pragma unroll
    for (int t = 0; t < 16; ++t) {
        const u16* krow = kb + ((size_t)(t * 16 + col) * NB + n) * EMB + h * HD;
        bf16x8 b0 = __builtin_bit_cast(bf16x8, *(const uint4*)(krow + quad * 8));
        bf16x8 b1 = __builtin_bit_cast(bf16x8, *(const uint4*)(krow + 32 + quad * 8));
        f32x4 acc = (f32x4){0.f, 0.f, 0.f, 0.f};
        acc = __builtin_amdgcn_mfma_f32_16x16x32_bf16(a0, b0, acc, 0, 0, 0);
        acc = __builtin_amdgcn_mfma_f32_16x16x32_bf16(a1, b1, acc, 0, 0, 0);
        sc[t] = acc;
    }

    #pragma unroll
    for (int reg = 0; reg < 4; ++reg) {
        const float* Srow = S + (((size_t)n * NH + h) * L_SEQ + i0 + quad * 4 + reg) * L_SEQ + col;
        float m = -1e30f;
        #pragma unroll
        for (int t = 0; t < 16; ++t) {
            float v = sc[t][reg] + Srow[t * 16];
            sc[t][reg] = v;
            m = fmaxf(m, v);
        }
        #pragma unroll
        for (int off = 1; off < 16; off <<= 1) m = fmaxf(m, __shfl_xor(m, off));
        float sum = 0.f;
        #pragma unroll
        for (int t = 0; t < 16; ++t) {
            float e = __expf(sc[t][reg] - m);
            sc[t][reg] = e;
            sum += e;
        }
        #pragma unroll
        for (int off = 1; off < 16; off <<= 1) sum += __shfl_xor(sum, off);
        float inv = 1.0f / sum;
        #pragma unroll
        for (int t = 0; t < 16; ++t)
            p_lds[wave][quad * 4 + reg][t * 16 + col] = f2b(sc[t][reg] * inv);
    }

    bf16x8 ap[8];
    #pragma unroll
    for (int kt = 0; kt < 8; ++kt)
        ap[kt] = __builtin_bit_cast(bf16x8, *(const uint4*)&p_lds[wave][col][kt * 32 + quad * 8]);
    #pragma unroll
    for (int nt = 0; nt < 4; ++nt) {
        const u16* vrow = vt + ((size_t)n * EMB + h * HD + nt * 16 + col) * L_SEQ;
        f32x4 acc = (f32x4){0.f, 0.f, 0.f, 0.f};
        #pragma unroll
        for (int kt = 0; kt < 8; ++kt) {
            bf16x8 bp = __builtin_bit_cast(bf16x8, *(const uint4*)(vrow + kt * 32 + quad * 8));
            acc = __builtin_amdgcn_mfma_f32_16x16x32_bf16(ap[kt], bp, acc, 0, 0, 0);
        }
        #pragma unroll
        for (int reg = 0; reg < 4; ++reg) {
            int ii = i0 + quad * 4 + reg;
            ctxb[((size_t)ii * NB + n) * EMB + h * HD + nt * 16 + col] = f2b(acc[reg]);
        }
    }
}

// ln1: y = p0 + p1 + src + out_bias; LN -> x1b (bf16); y2 = LN_out + lin2_bias.
__global__ void ln1_kernel(const float* __restrict__ p0, const float* __restrict__ p1,
                           const void* __restrict__ src, const float* __restrict__ biasf,
                           const void* __restrict__ g, const void* __restrict__ b,
                           u16* __restrict__ x1b, float* __restrict__ y2,
                           const int* __restrict__ flagp) {
    const int f32 = *flagp;
    int r = blockIdx.x;
    int t = threadIdx.x;
    __shared__ float red[256];
    float x[3];
    #pragma unroll
    for (int p = 0; p < 3; ++p) {
        int e = t + p * 256;
        size_t oi = (size_t)r * EMB + e;
        x[p] = p0[oi] + p1[oi] + ldE(src, oi, f32) + biasf[2304 + e];
    }
    red[t] = x[0] + x[1] + x[2];
    __syncthreads();
    for (int off = 128; off; off >>= 1) {
        if (t < off) red[t] += red[t + off];
        __syncthreads();
    }
    float mean = red[0] * (1.0f / EMB);
    __syncthreads();
    float d0 = x[0] - mean, d1 = x[1] - mean, d2 = x[2] - mean;
    red[t] = d0 * d0 + d1 * d1 + d2 * d2;
    __syncthreads();
    for (int off = 128; off; off >>= 1) {
        if (t < off) red[t] += red[t + off];
        __syncthreads();
    }
    float rstd = rsqrtf(red[0] * (1.0f / EMB) + 1e-5f);
    float vs[3] = {d0, d1, d2};
    #pragma unroll
    for (int p = 0; p < 3; ++p) {
        int e = t + p * 256;
        float v = vs[p] * rstd * ldE(g, e, f32) + ldE(b, e, f32);
        size_t oi = (size_t)r * EMB + e;
        x1b[oi] = f2b(v);
        y2[oi] = v + biasf[6144 + e];
    }
}

// ln2 (final): LN(y2) -> d_out runtime dtype.
__global__ void ln2_kernel(const float* __restrict__ X, const void* __restrict__ g,
                           const void* __restrict__ b, void* __restrict__ outAny,
                           const int* __restrict__ flagp) {
    const int f32 = *flagp;
    int r = blockIdx.x;
    int t = threadIdx.x;
    __shared__ float red[256];
    float x0 = X[(size_t)r * EMB + t];
    float x1 = X[(size_t)r * EMB + t + 256];
    float x2 = X[(size_t)r * EMB + t + 512];
    red[t] = x0 + x1 + x2;
    __syncthreads();
    for (int off = 128; off; off >>= 1) {
        if (t < off) red[t] += red[t + off];
        __syncthreads();
    }
    float mean = red[0] * (1.0f / EMB);
    __syncthreads();
    float d0 = x0 - mean, d1 = x1 - mean, d2 = x2 - mean;
    red[t] = d0 * d0 + d1 * d1 + d2 * d2;
    __syncthreads();
    for (int off = 128; off; off >>= 1) {
        if (t < off) red[t] += red[t + off];
        __syncthreads();
    }
    float rstd = rsqrtf(red[0] * (1.0f / EMB) + 1e-5f);
    float vs[3] = {d0, d1, d2};
    #pragma unroll
    for (int p = 0; p < 3; ++p) {
        int e = t + p * 256;
        float v = vs[p] * rstd * ldE(g, e, f32) + ldE(b, e, f32);
        size_t oi = (size_t)r * EMB + e;
        if (f32) ((float*)outAny)[oi] = v;
        else     ((bf16*)outAny)[oi] = __float2bfloat16(v);
    }
}

extern "C" void kernel_launch(void* const* d_in, const int* in_sizes, int n_in,
                              void* d_out, int out_size, void* d_ws, size_t ws_size,
                              hipStream_t stream) {
    const void* src    = d_in[0];
    const void* pos    = d_in[1];
    const void* q_w    = d_in[2];
    const void* q_b    = d_in[3];
    const void* k_w    = d_in[4];
    const void* k_b    = d_in[5];
    const void* v_w    = d_in[6];
    const void* v_b    = d_in[7];
    const void* p_w    = d_in[8];
    const void* p_b    = d_in[9];
    const void* out_w  = d_in[10];
    const void* out_b  = d_in[11];
    const void* lin1_w = d_in[12];
    const void* lin1_b = d_in[13];
    const void* lin2_w = d_in[14];
    const void* lin2_b = d_in[15];
    const void* n1_g   = d_in[16];
    const void* n1_b   = d_in[17];
    const void* n2_g   = d_in[18];
    const void* n2_b   = d_in[19];

    float* f = (float*)d_ws;
    int*   flagp = (int*)f;                              // 16
    float* biasf = f + 16;                               // 6912
    u16*   xb    = (u16*)(f + 6928);                     // 393216 f
    u16*   wqkv  = (u16*)(f + 400144);                   // 884736 f (dead after QKV gemm)
    u16*   owb   = (u16*)(f + 1284880);                  // 294912 f
    u16*   l1b   = (u16*)(f + 1579792);                  // 1179648 f
    u16*   l2b   = (u16*)(f + 2759440);                  // 1179648 f
    u16*   qbp   = (u16*)(f + 3939088);                  // 393216 f
    u16*   kbp   = (u16*)(f + 4332304);                  // 393216 f
    u16*   vtb   = (u16*)(f + 4725520);                  // 393216 f  vt[n][e][i]
    u16*   p_wT  = (u16*)(f + 5118736);                  // 49920 u16 -> 25088 f
    float* S     = f + 5143824;                          // 3145728 (ends 8289552)
    u16*   ctxb  = (u16*)(f + 8289552);                  // 393216 f (ends 8682768)
    // overlays (regions dead at time of use):
    u16*   ffb   = (u16*)S;                              // S[0 : 1572864]
    float* y2    = S + 1572864;                          // S[1572864 : 2359296]
    float* pOut1 = S + 2359296;                          // S[2359296 : 3145728]
    float* pOut0 = f + 400144;                           // wqkv region (dead)
    u16*   x1b   = vtb;                                  // vt dead after attn3

    pack_all<<<3892, 256, 0, stream>>>(xb, wqkv, owb, l1b, l2b, biasf, p_wT,
                                       src, q_w, k_w, v_w, out_w, lin1_w, lin2_w,
                                       q_b, k_b, v_b, out_b, lin1_b, lin2_b,
                                       p_w, p_b, flagp);

    // QKV fused GEMM (N=2304); V written transposed
    mfma_gemm<0><<<dim3(18, 8), 256, 0, stream>>>(
        xb, wqkv, biasf, qbp, kbp, vtb, nullptr, nullptr, EMB, EMB, 0);

    // fused qp + position scores
    s2q_mfma<<<NB * L_SEQ / 4, 256, 0, stream>>>(qbp, p_wT, pos, S, flagp);

    // MFMA attention
    attn3_kernel<<<NB * NH * 8, 128, 0, stream>>>(qbp, kbp, vtb, S, ctxb);

    // out projection, split-K=2 -> partials pOut0/pOut1 (bias+residual in ln1)
    mfma_gemm<4><<<dim3(6, 8, 2), 256, 0, stream>>>(
        ctxb, owb, nullptr, nullptr, nullptr, nullptr, pOut0, pOut1, 384, EMB, 384);

    // ln1: reduce partials + src + out_bias, LN -> x1b; y2 = LN + lin2_bias
    ln1_kernel<<<1024, 256, 0, stream>>>(pOut0, pOut1, src, biasf, n1_g, n1_b,
                                         x1b, y2, flagp);

    // lin1 + GELU -> ffb
    mfma_gemm<2><<<dim3(24, 8), 256, 0, stream>>>(
        x1b, l1b, biasf + 3072, ffb, nullptr, nullptr, nullptr, nullptr, EMB, EMB, 0);

    // lin2, split-K=4, atomic accumulate into y2 (pre-initialized by ln1)
    mfma_gemm<5><<<dim3(6, 8, 4), 256, 0, stream>>>(
        ffb, l2b, nullptr, nullptr, nullptr, nullptr, y2, nullptr, 768, DFF, 768);

    ln2_kernel<<<1024, 256, 0, stream>>>(y2, n2_g, n2_b, d_out, flagp);
}